// Round 1
// baseline (4019.277 us; speedup 1.0000x reference)
//
#include <hip/hip_runtime.h>
#include <stdint.h>

typedef unsigned short u16;
typedef __attribute__((ext_vector_type(8))) short short8;
typedef __attribute__((ext_vector_type(4))) float floatx4;

constexpr int BB = 128;     // batch
constexpr int TT = 64;      // time steps
constexpr int CC = 66;      // frame channels
constexpr int CPAD = 96;    // C padded to multiple of 32 (MFMA K-chunk)
constexpr int CPAD2 = 128;  // C padded for WsT epilogue GEMV
constexpr int SS = 512;     // hidden
constexpr int NGATE = 1536; // 3*S

__device__ __forceinline__ u16 f2bf(float f) {
    uint32_t u = __float_as_uint(f);
    uint32_t r = (u + 0x7fffu + ((u >> 16) & 1u)) >> 16;
    return (u16)r;
}
__device__ __forceinline__ float bf2f(u16 h) {
    return __uint_as_float(((uint32_t)h) << 16);
}
__device__ __forceinline__ float sigm(float x) { return 1.f / (1.f + __expf(-x)); }
__device__ __forceinline__ float tanh_f(float x) { return 1.f - 2.f / (1.f + __expf(2.f * x)); }

// ---------------------------------------------------------------------------
// One-time prep: fp32 -> bf16 weight/x conversion with zero padding, Ws
// transpose (512 x CPAD2, zero-padded), decoder input init from x[:, T-1, :].
// ---------------------------------------------------------------------------
__global__ void prep_kernel(const float* __restrict__ x,
                            const float* __restrict__ Wih0,
                            const float* __restrict__ Whh0,
                            const float* __restrict__ Wih1,
                            const float* __restrict__ Whh1,
                            const float* __restrict__ Ws,
                            u16* __restrict__ xbf, u16* __restrict__ wi0,
                            u16* __restrict__ wh0, u16* __restrict__ wi1,
                            u16* __restrict__ wh1, float* __restrict__ wst,
                            float* __restrict__ dinp_f, u16* __restrict__ dinp_bf)
{
    const int N_xbf = BB * TT * CPAD;   // 786432   [b][t][c96]
    const int N_wi0 = NGATE * CPAD;     // 147456   [n][c96]
    const int N_whh = NGATE * SS;       // 786432
    const int N_wst = SS * CPAD2;       // 65536    [s][c128]
    const int N_dinp = BB * CPAD;       // 12288
    const long total = (long)N_xbf + N_wi0 + 3L * N_whh + N_wst + N_dinp;
    for (long i = (long)blockIdx.x * blockDim.x + threadIdx.x; i < total;
         i += (long)gridDim.x * blockDim.x) {
        long idx = i;
        if (idx < N_xbf) {
            int c = idx % CPAD; int bt = idx / CPAD;   // bt = b*T + t
            float v = (c < CC) ? x[(long)bt * CC + c] : 0.f;
            xbf[idx] = f2bf(v); continue;
        }
        idx -= N_xbf;
        if (idx < N_wi0) {
            int c = idx % CPAD; int n = idx / CPAD;
            float v = (c < CC) ? Wih0[(long)n * CC + c] : 0.f;
            wi0[idx] = f2bf(v); continue;
        }
        idx -= N_wi0;
        if (idx < N_whh) { wh0[idx] = f2bf(Whh0[idx]); continue; }
        idx -= N_whh;
        if (idx < N_whh) { wi1[idx] = f2bf(Wih1[idx]); continue; }
        idx -= N_whh;
        if (idx < N_whh) { wh1[idx] = f2bf(Whh1[idx]); continue; }
        idx -= N_whh;
        if (idx < N_wst) {
            int c = idx % CPAD2; int s = idx / CPAD2;
            wst[idx] = (c < CC) ? Ws[(long)c * SS + s] : 0.f;  // transpose
            continue;
        }
        idx -= N_wst;
        {
            int c = idx % CPAD; int b = idx / CPAD;
            float v = (c < CC) ? x[((long)b * TT + (TT - 1)) * CC + c] : 0.f;
            dinp_bf[idx] = f2bf(v);
            if (c < CC) dinp_f[(long)b * CC + c] = v;
        }
    }
}

// ---------------------------------------------------------------------------
// Fused GRU cell: h_new = (1-z)*n + z*h_old
//   gi = A @ Wih^T (+bih), gh = h_old @ Whh^T (+bhh)
//   r = sig(gi_r+gh_r), z = sig(gi_z+gh_z), n = tanh(gi_n + r*gh_n)
// Grid: (B/32, S/32), 256 threads = 4 waves; wave = 16b x 16s quadrant,
// 3 gates via 4 MFMA accumulators (r,z merged; n-gate i/h kept separate).
// Fragments loaded directly from global (bf16, K-contiguous rows).
// ---------------------------------------------------------------------------
template <int KIN>
__global__ __launch_bounds__(256) void gru_cell_kernel(
    const u16* __restrict__ Abf, int ldA,
    const u16* __restrict__ Wibf,          // [1536][KIN]
    const u16* __restrict__ Hbf,           // [128][512] bf16 h_old
    const u16* __restrict__ Whbf,          // [1536][512]
    const float* __restrict__ bih, const float* __restrict__ bhh,
    const float* __restrict__ hold_f,      // [128][512] fp32 h_old
    float* __restrict__ hnew_f, u16* __restrict__ hnew_bf,
    u16* __restrict__ win_slot)            // optional extra bf16 copy (window)
{
    const int tid = threadIdx.x;
    const int wave = tid >> 6, lane = tid & 63;
    const int msub = wave & 1, ssub = wave >> 1;
    const int b0 = blockIdx.x * 32 + msub * 16;
    const int s0 = blockIdx.y * 32 + ssub * 16;
    const int l15 = lane & 15, quad = lane >> 4;

    floatx4 accR = {0.f, 0.f, 0.f, 0.f};
    floatx4 accZ = accR, accNI = accR, accNH = accR;

    // x-phase (input contribution): updates r, z, n_i
    {
        const u16* aP  = Abf + (long)(b0 + l15) * ldA + quad * 8;
        const u16* wrP = Wibf + (long)(s0 + l15) * KIN + quad * 8;
        const u16* wzP = Wibf + (long)(512 + s0 + l15) * KIN + quad * 8;
        const u16* wnP = Wibf + (long)(1024 + s0 + l15) * KIN + quad * 8;
#pragma unroll
        for (int k = 0; k < KIN; k += 32) {
            short8 a  = *(const short8*)(aP + k);
            short8 br = *(const short8*)(wrP + k);
            short8 bz = *(const short8*)(wzP + k);
            short8 bn = *(const short8*)(wnP + k);
            accR  = __builtin_amdgcn_mfma_f32_16x16x32_bf16(a, br, accR, 0, 0, 0);
            accZ  = __builtin_amdgcn_mfma_f32_16x16x32_bf16(a, bz, accZ, 0, 0, 0);
            accNI = __builtin_amdgcn_mfma_f32_16x16x32_bf16(a, bn, accNI, 0, 0, 0);
        }
    }
    // h-phase (hidden contribution): updates r, z, n_h
    {
        const u16* hP  = Hbf + (long)(b0 + l15) * SS + quad * 8;
        const u16* wrP = Whbf + (long)(s0 + l15) * SS + quad * 8;
        const u16* wzP = Whbf + (long)(512 + s0 + l15) * SS + quad * 8;
        const u16* wnP = Whbf + (long)(1024 + s0 + l15) * SS + quad * 8;
#pragma unroll
        for (int k = 0; k < SS; k += 32) {
            short8 a  = *(const short8*)(hP + k);
            short8 br = *(const short8*)(wrP + k);
            short8 bz = *(const short8*)(wzP + k);
            short8 bn = *(const short8*)(wnP + k);
            accR  = __builtin_amdgcn_mfma_f32_16x16x32_bf16(a, br, accR, 0, 0, 0);
            accZ  = __builtin_amdgcn_mfma_f32_16x16x32_bf16(a, bz, accZ, 0, 0, 0);
            accNH = __builtin_amdgcn_mfma_f32_16x16x32_bf16(a, bn, accNH, 0, 0, 0);
        }
    }
    // epilogue: D layout row=(lane>>4)*4+reg (b), col=lane&15 (s)
    const int s = s0 + l15;
    const float bir = bih[s] + bhh[s];
    const float biz = bih[512 + s] + bhh[512 + s];
    const float bin = bih[1024 + s];
    const float bhn = bhh[1024 + s];
#pragma unroll
    for (int r = 0; r < 4; ++r) {
        const int b = b0 + quad * 4 + r;
        float rr = sigm(accR[r] + bir);
        float zz = sigm(accZ[r] + biz);
        float nn = tanh_f(accNI[r] + bin + rr * (accNH[r] + bhn));
        float ho = hold_f[(long)b * SS + s];
        float hv = (1.f - zz) * nn + zz * ho;
        hnew_f[(long)b * SS + s] = hv;
        u16 hb = f2bf(hv);
        hnew_bf[(long)b * SS + s] = hb;
        if (win_slot) win_slot[(long)b * SS + s] = hb;
    }
}

// ---------------------------------------------------------------------------
// Decoder output step: temp[b][s] = bt + sum_j win[(1+d+j)%32][b][s]*Wt[j]
//   out[b][c] = bs[c] + sum_s temp[s]*Ws[c][s];  frame = out + dinp
// One block per batch element.
// ---------------------------------------------------------------------------
__global__ __launch_bounds__(256) void out_step_kernel(
    const u16* __restrict__ winb, int d,
    const float* __restrict__ Wt, const float* __restrict__ bt,
    const float* __restrict__ wst /* [512][CPAD2] transposed Ws */,
    const float* __restrict__ bs,
    float* __restrict__ dinp_f, u16* __restrict__ dinp_bf,
    float* __restrict__ outp)
{
    const int b = blockIdx.x, tid = threadIdx.x;
    __shared__ float ts[SS];
    __shared__ float red[4][CPAD2];
    __shared__ float wts[32];
    if (tid < 32) wts[tid] = Wt[tid];
    __syncthreads();
    const float btv = bt[0];
    for (int s = tid; s < SS; s += 256) {
        float acc = btv;
#pragma unroll
        for (int j = 0; j < 32; ++j) {
            int slot = (1 + d + j) & 31;
            acc += bf2f(winb[(long)slot * (BB * SS) + (long)b * SS + s]) * wts[j];
        }
        ts[s] = acc;
    }
    __syncthreads();
    const int w = tid >> 6, lane = tid & 63;
    float a0 = 0.f, a1 = 0.f;
    for (int s = w * 128; s < w * 128 + 128; ++s) {
        float tv = ts[s];
        a0 += tv * wst[(long)s * CPAD2 + lane];
        a1 += tv * wst[(long)s * CPAD2 + 64 + lane];
    }
    red[w][lane] = a0;
    red[w][64 + lane] = a1;
    __syncthreads();
    if (tid < CC) {
        const int c = tid;
        float v = bs[c] + red[0][c] + red[1][c] + red[2][c] + red[3][c];
        float fr = v + dinp_f[(long)b * CC + c];
        outp[(long)b * (TT * CC) + (long)d * CC + c] = fr;
        dinp_f[(long)b * CC + c] = fr;
        dinp_bf[(long)b * CPAD + c] = f2bf(fr);
    }
}

// ---------------------------------------------------------------------------
extern "C" void kernel_launch(void* const* d_in, const int* in_sizes, int n_in,
                              void* d_out, int out_size, void* d_ws, size_t ws_size,
                              hipStream_t stream)
{
    const float* x    = (const float*)d_in[0];
    const float* Wih0 = (const float*)d_in[1];
    const float* Whh0 = (const float*)d_in[2];
    const float* bih0 = (const float*)d_in[3];
    const float* bhh0 = (const float*)d_in[4];
    const float* Wih1 = (const float*)d_in[5];
    const float* Whh1 = (const float*)d_in[6];
    const float* bih1 = (const float*)d_in[7];
    const float* bhh1 = (const float*)d_in[8];
    const float* Wt   = (const float*)d_in[9];
    const float* bt   = (const float*)d_in[10];
    const float* Ws   = (const float*)d_in[11];
    const float* bs   = (const float*)d_in[12];
    float* outp = (float*)d_out;

    char* p = (char*)d_ws;
    auto alloc = [&](size_t bytes) -> char* {
        char* r = p; p += (bytes + 255) & ~(size_t)255; return r;
    };
    float* h0f[2] = {(float*)alloc(BB * SS * 4), (float*)alloc(BB * SS * 4)};
    float* h1f[2] = {(float*)alloc(BB * SS * 4), (float*)alloc(BB * SS * 4)};
    u16* h0b[2] = {(u16*)alloc(BB * SS * 2), (u16*)alloc(BB * SS * 2)};
    u16* h1b[2] = {(u16*)alloc(BB * SS * 2), (u16*)alloc(BB * SS * 2)};
    u16* xbf = (u16*)alloc((size_t)BB * TT * CPAD * 2);
    u16* wi0 = (u16*)alloc((size_t)NGATE * CPAD * 2);
    u16* wh0 = (u16*)alloc((size_t)NGATE * SS * 2);
    u16* wi1 = (u16*)alloc((size_t)NGATE * SS * 2);
    u16* wh1 = (u16*)alloc((size_t)NGATE * SS * 2);
    float* wst = (float*)alloc((size_t)SS * CPAD2 * 4);
    u16* winb = (u16*)alloc((size_t)32 * BB * SS * 2);
    float* dinp_f = (float*)alloc(BB * CC * 4);
    u16* dinp_bf = (u16*)alloc(BB * CPAD * 2);

    // zero initial hidden state (ws is poisoned before every call)
    hipMemsetAsync(h0f[0], 0, BB * SS * 4, stream);
    hipMemsetAsync(h1f[0], 0, BB * SS * 4, stream);
    hipMemsetAsync(h0b[0], 0, BB * SS * 2, stream);
    hipMemsetAsync(h1b[0], 0, BB * SS * 2, stream);

    prep_kernel<<<1024, 256, 0, stream>>>(x, Wih0, Whh0, Wih1, Whh1, Ws,
                                          xbf, wi0, wh0, wi1, wh1, wst,
                                          dinp_f, dinp_bf);

    dim3 cgrid(BB / 32, SS / 32);  // (4,16) = 64 blocks
    int pp = 0;
    // encoder: t = 0..62
    for (int t = 0; t < TT - 1; ++t) {
        gru_cell_kernel<CPAD><<<cgrid, 256, 0, stream>>>(
            xbf + (long)t * CPAD, TT * CPAD, wi0, h0b[pp], wh0, bih0, bhh0,
            h0f[pp], h0f[1 - pp], h0b[1 - pp], nullptr);
        u16* wslot = (t >= 31) ? (winb + (size_t)(t - 31) * (BB * SS)) : nullptr;
        gru_cell_kernel<SS><<<cgrid, 256, 0, stream>>>(
            h0b[1 - pp], SS, wi1, h1b[pp], wh1, bih1, bhh1,
            h1f[pp], h1f[1 - pp], h1b[1 - pp], wslot);
        pp ^= 1;
    }
    // decoder: d = 0..63
    for (int d = 0; d < TT; ++d) {
        gru_cell_kernel<CPAD><<<cgrid, 256, 0, stream>>>(
            dinp_bf, CPAD, wi0, h0b[pp], wh0, bih0, bhh0,
            h0f[pp], h0f[1 - pp], h0b[1 - pp], nullptr);
        gru_cell_kernel<SS><<<cgrid, 256, 0, stream>>>(
            h0b[1 - pp], SS, wi1, h1b[pp], wh1, bih1, bhh1,
            h1f[pp], h1f[1 - pp], h1b[1 - pp],
            winb + (size_t)(d & 31) * (BB * SS));
        out_step_kernel<<<BB, 256, 0, stream>>>(winb, d, Wt, bt, wst, bs,
                                                dinp_f, dinp_bf, outp);
        pp ^= 1;
    }
}